// Round 2
// baseline (9809.947 us; speedup 1.0000x reference)
//
#include <hip/hip_runtime.h>
#include <hip/hip_bf16.h>

#define T_STEPS 2048
#define NB      64
#define IN_DIM  300
#define HID     512

typedef __attribute__((ext_vector_type(8))) short short8;   // 8 bf16 (4 VGPR)
typedef __attribute__((ext_vector_type(4))) float f32x4;    // MFMA accumulator

static __device__ __forceinline__ unsigned short f2bf(float x) {
    unsigned int u = __float_as_uint(x);
    u = u + 0x7FFFu + ((u >> 16) & 1u);          // round-to-nearest-even
    return (unsigned short)(u >> 16);
}
static __device__ __forceinline__ float bf2f(unsigned short h) {
    return __uint_as_float(((unsigned int)h) << 16);
}

// ---------------------------------------------------------------------------
// Kernel 1: U = bf16( x_t W_ih^T + b_ih + b_hh ), written in rec-fragment
// order: U[t][g(4)][jt(32)][lane(64)][r(4)]  (g=b>>4, lane=(m>>2)<<4|jc, r=m&3)
// so rnn_rec loads one coalesced dwordx2 per (lane, tile).
// ---------------------------------------------------------------------------
__global__ __launch_bounds__(256, 4) void u_gemm(
    const float* __restrict__ X, const float* __restrict__ Wih,
    const float* __restrict__ bih, const float* __restrict__ bhh,
    unsigned short* __restrict__ U)
{
    __shared__ unsigned short As[64 * 160];
    __shared__ unsigned short Bs[64 * 160];
    const int tid = threadIdx.x;
    const int m0 = (blockIdx.x >> 3) * 64, n0 = (blockIdx.x & 7) * 64;
    const int w = tid >> 6, l = tid & 63;

    const f32x4 zv = {0.f, 0.f, 0.f, 0.f};
    f32x4 acc00 = zv, acc01 = zv, acc10 = zv, acc11 = zv;

    for (int kh = 0; kh < 2; ++kh) {
        const int kbase = kh * 160;
        __syncthreads();
        for (int i = tid; i < 64 * 40; i += 256) {
            const int r = i / 40, q = i - r * 40;
            const int kg = kbase + q * 4;
            unsigned int a0 = 0, a1 = 0, b0 = 0, b1 = 0;
            if (kg + 4 <= IN_DIM) {
                const float4 v = *reinterpret_cast<const float4*>(X + (size_t)(m0 + r) * IN_DIM + kg);
                a0 = (unsigned)f2bf(v.x) | ((unsigned)f2bf(v.y) << 16);
                a1 = (unsigned)f2bf(v.z) | ((unsigned)f2bf(v.w) << 16);
                const float4 u = *reinterpret_cast<const float4*>(Wih + (size_t)(n0 + r) * IN_DIM + kg);
                b0 = (unsigned)f2bf(u.x) | ((unsigned)f2bf(u.y) << 16);
                b1 = (unsigned)f2bf(u.z) | ((unsigned)f2bf(u.w) << 16);
            }
            int byte = r * 320 + q * 8; byte ^= ((r & 7) << 4);
            *reinterpret_cast<uint2*>(reinterpret_cast<char*>(As) + byte) = make_uint2(a0, a1);
            *reinterpret_cast<uint2*>(reinterpret_cast<char*>(Bs) + byte) = make_uint2(b0, b1);
        }
        __syncthreads();
        #pragma unroll
        for (int kc = 0; kc < 5; ++kc) {
            const int koff = kc * 64 + (l >> 4) * 16;
            short8 a[2], b[2];
            #pragma unroll
            for (int mt = 0; mt < 2; ++mt) {
                const int row = (w >> 1) * 32 + mt * 16 + (l & 15);
                int abyte = row * 320 + koff; abyte ^= ((row & 7) << 4);
                a[mt] = *reinterpret_cast<const short8*>(reinterpret_cast<const char*>(As) + abyte);
                const int jrow = (w & 1) * 32 + mt * 16 + (l & 15);
                int bbyte = jrow * 320 + koff; bbyte ^= ((jrow & 7) << 4);
                b[mt] = *reinterpret_cast<const short8*>(reinterpret_cast<const char*>(Bs) + bbyte);
            }
            acc00 = __builtin_amdgcn_mfma_f32_16x16x32_bf16(a[0], b[0], acc00, 0, 0, 0);
            acc01 = __builtin_amdgcn_mfma_f32_16x16x32_bf16(a[0], b[1], acc01, 0, 0, 0);
            acc10 = __builtin_amdgcn_mfma_f32_16x16x32_bf16(a[1], b[0], acc10, 0, 0, 0);
            acc11 = __builtin_amdgcn_mfma_f32_16x16x32_bf16(a[1], b[1], acc11, 0, 0, 0);
        }
    }
    const int t = blockIdx.x >> 3;
    #pragma unroll
    for (int nt = 0; nt < 2; ++nt) {
        const int col = n0 + (w & 1) * 32 + nt * 16 + (l & 15);
        const float bias = bih[col] + bhh[col];
        const int jt = col >> 4;
        #pragma unroll
        for (int mt = 0; mt < 2; ++mt) {
            const f32x4 acc = (mt == 0) ? (nt == 0 ? acc00 : acc01)
                                        : (nt == 0 ? acc10 : acc11);
            const int g = (w >> 1) * 2 + mt;        // batch-group 0..3
            const size_t idx = ((((size_t)t * 4 + g) * 32 + jt) * 64 + l) * 4;
            uint2 p;
            p.x = (unsigned)f2bf(acc[0] + bias) | ((unsigned)f2bf(acc[1] + bias) << 16);
            p.y = (unsigned)f2bf(acc[2] + bias) | ((unsigned)f2bf(acc[3] + bias) << 16);
            *reinterpret_cast<uint2*>(U + idx) = p;
        }
    }
}

// ---------------------------------------------------------------------------
// Kernel 2: recurrence, ZERO inter-block communication. 4 blocks x 512 thr;
// block g owns batches g*16..g*16+15 and all 512 hidden cols. W_hh bf16:
// k-chunks 0..11 stationary in VGPRs (192/lane), chunks 12..15 in LDS (128KB,
// linear fragment order, conflict-free). h: one 16KB XOR-swizzled LDS buffer.
// Per step: 512 MFMA (16x16x32), 2 barriers, U loads hidden under MFMA phase.
// ---------------------------------------------------------------------------
__global__ __launch_bounds__(512, 2) void rnn_rec(
    const float* __restrict__ Whh, const unsigned short* __restrict__ Uf,
    float* __restrict__ out)
{
    const int g = blockIdx.x;                // 0..3
    const int tid = threadIdx.x;
    const int w = tid >> 6, l = tid & 63;
    const int lq = l >> 4, lr = l & 15;

    __shared__ unsigned short h_lds[16 * 512];          // 16 KB
    __shared__ unsigned short w_lds[4 * 32 * 64 * 8];   // 128 KB [kp][jt][lane][e]

    // --- stationary VGPR weights: tiles w*4..w*4+3, k-chunks 0..11
    short8 bfr[4][12];
    #pragma unroll
    for (int c = 0; c < 4; ++c) {
        const int j0 = (w * 4 + c) * 16 + lr;
        #pragma unroll
        for (int kc = 0; kc < 12; ++kc) {
            const int k0 = kc * 32 + lq * 8;
            const float4 v0 = *reinterpret_cast<const float4*>(Whh + (size_t)j0 * HID + k0);
            const float4 v1 = *reinterpret_cast<const float4*>(Whh + (size_t)j0 * HID + k0 + 4);
            short8 f;
            f[0] = (short)f2bf(v0.x); f[1] = (short)f2bf(v0.y);
            f[2] = (short)f2bf(v0.z); f[3] = (short)f2bf(v0.w);
            f[4] = (short)f2bf(v1.x); f[5] = (short)f2bf(v1.y);
            f[6] = (short)f2bf(v1.z); f[7] = (short)f2bf(v1.w);
            bfr[c][kc] = f;
        }
    }
    // --- LDS weights: k-chunks 12..15, fragment-linear (lane-contiguous)
    #pragma unroll
    for (int c = 0; c < 4; ++c) {
        const int jt = w * 4 + c;
        const int j0 = jt * 16 + lr;
        #pragma unroll
        for (int kp = 0; kp < 4; ++kp) {
            const int k0 = (12 + kp) * 32 + lq * 8;
            const float4 v0 = *reinterpret_cast<const float4*>(Whh + (size_t)j0 * HID + k0);
            const float4 v1 = *reinterpret_cast<const float4*>(Whh + (size_t)j0 * HID + k0 + 4);
            short8 f;
            f[0] = (short)f2bf(v0.x); f[1] = (short)f2bf(v0.y);
            f[2] = (short)f2bf(v0.z); f[3] = (short)f2bf(v0.w);
            f[4] = (short)f2bf(v1.x); f[5] = (short)f2bf(v1.y);
            f[6] = (short)f2bf(v1.z); f[7] = (short)f2bf(v1.w);
            *reinterpret_cast<short8*>(&w_lds[(((size_t)kp * 32 + jt) * 64 + l) * 8]) = f;
        }
    }
    // --- h0 = 0
    for (int i = tid * 8; i < 16 * 512; i += 512 * 8)
        *reinterpret_cast<uint4*>(&h_lds[i]) = make_uint4(0, 0, 0, 0);
    __syncthreads();

    const int abase = lr * 1024 + lq * 16;     // bytes into h_lds
    const int aswz  = (lr & 7) << 4;
    const char* hcr = reinterpret_cast<const char*>(h_lds);
    char* hcw = reinterpret_cast<char*>(h_lds);
    const size_t ubase = (((size_t)g * 32 + w * 4) * 64 + l) * 4;  // +t*32768 +c*256

    for (int t = 0; t < T_STEPS; ++t) {
        // current-step U (latency hidden under the MFMA phase)
        const unsigned short* up = Uf + (size_t)t * 32768 + ubase;
        const uint2 u0 = *reinterpret_cast<const uint2*>(up + 0 * 256);
        const uint2 u1 = *reinterpret_cast<const uint2*>(up + 1 * 256);
        const uint2 u2 = *reinterpret_cast<const uint2*>(up + 2 * 256);
        const uint2 u3 = *reinterpret_cast<const uint2*>(up + 3 * 256);

        f32x4 acc0 = {0.f,0.f,0.f,0.f}, acc1 = {0.f,0.f,0.f,0.f};
        f32x4 acc2 = {0.f,0.f,0.f,0.f}, acc3 = {0.f,0.f,0.f,0.f};
        #pragma unroll
        for (int kc = 0; kc < 16; ++kc) {
            const int byte = (abase + kc * 64) ^ aswz;
            const short8 a = *reinterpret_cast<const short8*>(hcr + byte);
            short8 b0, b1, b2, b3;
            if (kc < 12) {
                b0 = bfr[0][kc]; b1 = bfr[1][kc]; b2 = bfr[2][kc]; b3 = bfr[3][kc];
            } else {
                const int kp = kc - 12;
                const size_t wb = (((size_t)kp * 32 + w * 4) * 64 + l) * 8;
                b0 = *reinterpret_cast<const short8*>(&w_lds[wb + 0 * 64 * 8]);
                b1 = *reinterpret_cast<const short8*>(&w_lds[wb + 1 * 64 * 8]);
                b2 = *reinterpret_cast<const short8*>(&w_lds[wb + 2 * 64 * 8]);
                b3 = *reinterpret_cast<const short8*>(&w_lds[wb + 3 * 64 * 8]);
            }
            acc0 = __builtin_amdgcn_mfma_f32_16x16x32_bf16(a, b0, acc0, 0, 0, 0);
            acc1 = __builtin_amdgcn_mfma_f32_16x16x32_bf16(a, b1, acc1, 0, 0, 0);
            acc2 = __builtin_amdgcn_mfma_f32_16x16x32_bf16(a, b2, acc2, 0, 0, 0);
            acc3 = __builtin_amdgcn_mfma_f32_16x16x32_bf16(a, b3, acc3, 0, 0, 0);
        }

        // tanh(acc + u): 16 values/lane -> bf16 packed
        unsigned short hb[4][4];
        {
            const f32x4 av[4] = {acc0, acc1, acc2, acc3};
            const uint2  uv[4] = {u0, u1, u2, u3};
            if (t == T_STEPS - 1) {
                #pragma unroll
                for (int c = 0; c < 4; ++c) {
                    const int col = (w * 4 + c) * 16 + lr;
                    #pragma unroll
                    for (int r = 0; r < 4; ++r) {
                        const unsigned short ub = (r < 2)
                            ? (unsigned short)(uv[c].x >> (16 * r))
                            : (unsigned short)(uv[c].y >> (16 * (r - 2)));
                        const float x = av[c][r] + bf2f(ub);
                        const float th = 1.f - 2.f / (__expf(2.f * x) + 1.f);
                        out[(size_t)(g * 16 + lq * 4 + r) * HID + col] = th;
                    }
                }
                return;
            }
            #pragma unroll
            for (int c = 0; c < 4; ++c) {
                #pragma unroll
                for (int r = 0; r < 4; ++r) {
                    const unsigned short ub = (r < 2)
                        ? (unsigned short)(uv[c].x >> (16 * r))
                        : (unsigned short)(uv[c].y >> (16 * (r - 2)));
                    const float x = av[c][r] + bf2f(ub);
                    hb[c][r] = f2bf(1.f - 2.f / (__expf(2.f * x) + 1.f));
                }
            }
        }

        __syncthreads();   // all reads of h(t) complete
        #pragma unroll
        for (int c = 0; c < 4; ++c) {
            const int col2 = ((w * 4 + c) * 16 + lr) * 2;
            #pragma unroll
            for (int r = 0; r < 4; ++r) {
                const int m = lq * 4 + r;
                const int byte = (m * 1024 + col2) ^ ((m & 7) << 4);
                *reinterpret_cast<unsigned short*>(hcw + byte) = hb[c][r];
            }
        }
        __syncthreads();   // h(t+1) visible to all waves
    }
}

// ---------------------------------------------------------------------------
extern "C" void kernel_launch(void* const* d_in, const int* in_sizes, int n_in,
                              void* d_out, int out_size, void* d_ws, size_t ws_size,
                              hipStream_t stream) {
    const float* X   = (const float*)d_in[0];   // [2048][64][300]
    const float* Wih = (const float*)d_in[1];   // [512][300]
    const float* Whh = (const float*)d_in[2];   // [512][512]
    const float* bih = (const float*)d_in[3];   // [512]
    const float* bhh = (const float*)d_in[4];   // [512]
    float* out = (float*)d_out;                 // [64][512]
    unsigned short* U = (unsigned short*)d_ws;  // 134.2 MB, fragment order

    u_gemm<<<dim3(2048 * 8), dim3(256), 0, stream>>>(X, Wih, bih, bhh, U);
    rnn_rec<<<dim3(4), dim3(512), 0, stream>>>(Whh, U, out);
}